// Round 8
// baseline (171.448 us; speedup 1.0000x reference)
//
#include <hip/hip_runtime.h>

typedef __attribute__((ext_vector_type(8))) short short8;
typedef __attribute__((ext_vector_type(4))) short short4v;
typedef __attribute__((ext_vector_type(4))) float floatx4;
typedef __attribute__((ext_vector_type(2))) float floatx2;  // native vec: ok for NT builtins

// fp32 -> bf16 round-to-nearest-even (inputs finite)
static __device__ __forceinline__ unsigned short f2bf(float f) {
    union { float f; unsigned int u; } v; v.f = f;
    unsigned int u = v.u;
    return (unsigned short)((u + 0x7FFFu + ((u >> 16) & 1u)) >> 16);
}
static __device__ __forceinline__ float bf2f(short x) {
    return __uint_as_float(((unsigned int)(unsigned short)x) << 16);
}

// W1 [256,128] fp32 -> WT [256,128] bf16:
//   n' <  128: WT[n'][k] = W1[k][n']        (Y1 cols, k = top half)
//   n' >= 128: WT[n'][k] = W1[128+k][n'-128] (Y2 cols, k = bottom half)
__global__ void cvt_wt_kernel(const float* __restrict__ w1,
                              unsigned short* __restrict__ wt) {
    __shared__ unsigned short sT[32 * 130];
    const int b = blockIdx.x;            // 0..7 -> W1 k-rows [b*32, b*32+32)
    const int kg0 = b * 32;
    const int h = (kg0 >= 128) ? 1 : 0;
    const int kk0 = kg0 & 127;
    const int tid = threadIdx.x;
#pragma unroll
    for (int i = 0; i < 16; i++) {       // load 32x128, coalesced in n
        int idx = tid + i * 256;
        int k = idx >> 7, n = idx & 127;
        sT[k * 130 + n] = f2bf(w1[(kg0 + k) * 128 + n]);
    }
    __syncthreads();
#pragma unroll
    for (int i = 0; i < 16; i++) {       // store, coalesced in k
        int idx = tid + i * 256;
        int n = idx >> 5, k = idx & 31;
        wt[(h * 128 + n) * 128 + kk0 + k] = sT[k * 130 + n];
    }
}

// Phase 1 v4: Y[n] = [x_n@W1_top + b1 | x_n@W1_bot], bf16, IN-PLACE over X.
// r7 structure (X-tile in 32KB LDS, coalesced staging, WT A-frags from
// L2-hot global held in VGPRs) + NT stores for Y: Y has zero reuse inside
// this kernel, so write-through keeps per-XCD L2s clean for edge_kernel's
// random gathers (r7 post-mortem: dirty-Y L2 handover is the suspected
// cause of edge 48.5 -> 64.8 µs).
// In-place safety: all global X reads precede the staging barrier; stores
// after it; blocks own disjoint row ranges. xy NOT __restrict__.
__global__ __launch_bounds__(512, 4) void node_gemm_kernel(
    float* xy,                                 // in: X fp32 [N,128]; out: Y bf16 [N,256]
    const unsigned short* __restrict__ wt,     // [256,128] bf16 (pre-transposed)
    const float* __restrict__ b1, int N)
{
    __shared__ unsigned short sX[128 * 128];   // 32KB X-tile, slot-swizzled

    const int tid = threadIdx.x;
    const int lane = tid & 63, wave = tid >> 6;
    const int l15 = lane & 15, lq = lane >> 4;
    const int row0 = blockIdx.x * 128;

    // A-fragments: wave's fixed 64-outcol slice, all 4 k-steps. 16 loads,
    // L2-hot (WT = 64KB), held in 64 VGPRs for the whole block.
    const int cs = wave & 3;                   // column slice (cs*64 .. +64)
    short8 af[4][4];
#pragma unroll
    for (int mt = 0; mt < 4; mt++)
#pragma unroll
        for (int ks = 0; ks < 4; ks++)
            af[mt][ks] = *(const short8*)
                &wt[(cs * 64 + mt * 16 + l15) * 128 + ks * 32 + lq * 8];

    // Stage X-tile: fully coalesced (32 consecutive threads = one 512B row).
    // Slot swizzle s -> s^(n&15) (same scheme as r4/r6 sW: measured 0 conflicts).
#pragma unroll
    for (int i = 0; i < 8; i++) {
        int u = tid + i * 512;                 // float4-unit id, 0..4095
        int n = u >> 5, f4 = u & 31;           // row-in-tile, float4-in-row
        int rr = row0 + n; if (rr >= N) rr = N - 1;
        const float4 xv = *(const float4*)(xy + (size_t)rr * 128 + f4 * 4);
        short4v pk;
        pk[0] = (short)f2bf(xv.x); pk[1] = (short)f2bf(xv.y);
        pk[2] = (short)f2bf(xv.z); pk[3] = (short)f2bf(xv.w);
        int s = f4 >> 1, hh = f4 & 1;          // 16B-slot, half
        *(short4v*)&sX[n * 128 + ((s ^ (n & 15)) * 16 + hh * 8) / 2] = pk;
    }
    __syncthreads();

    // 4 row-tile tasks per wave (rt = rt0, rt0+2, rt0+4, rt0+6).
    const int rt0 = wave >> 2;
#pragma unroll
    for (int j = 0; j < 4; j++) {
        const int rt = rt0 + j * 2;
        floatx4 acc[4];
#pragma unroll
        for (int mt = 0; mt < 4; mt++) acc[mt] = (floatx4){0.f, 0.f, 0.f, 0.f};
#pragma unroll
        for (int ks = 0; ks < 4; ks++) {
            const int n = rt * 16 + l15;       // node-in-tile (B-frag col)
            const short8 bf = *(const short8*)
                &sX[n * 128 + (((ks * 4 + lq) ^ l15) & 15) * 8];
#pragma unroll
            for (int mt = 0; mt < 4; mt++)
                acc[mt] = __builtin_amdgcn_mfma_f32_16x16x32_bf16(
                    af[mt][ks], bf, acc[mt], 0, 0, 0);
        }
        const int nr = row0 + rt * 16 + l15;   // C col = node
        if (nr < N) {
            unsigned short* yrow = (unsigned short*)xy + (size_t)nr * 256;
#pragma unroll
            for (int mt = 0; mt < 4; mt++) {
                const int oc = cs * 64 + mt * 16 + lq * 4;  // C row = outcol
                float4 bb = (oc < 128) ? *(const float4*)&b1[oc]
                                       : (float4){0.f, 0.f, 0.f, 0.f};
                short4v pk;
                pk[0] = (short)f2bf(acc[mt][0] + bb.x);
                pk[1] = (short)f2bf(acc[mt][1] + bb.y);
                pk[2] = (short)f2bf(acc[mt][2] + bb.z);
                pk[3] = (short)f2bf(acc[mt][3] + bb.w);
                __builtin_nontemporal_store(pk, (short4v*)(yrow + oc));  // 8B NT
            }
        }
    }
}

// Phase 2: pure gather + reduce. out[e] = relu(Y1[s]+Y2[d]) @ W2 + b2.
// FROZEN at the measured per-CU demand ceiling (~6.7 TB/s at L1-miss level;
// r1-r6: every structure — occupancy 2x, barrier-free, double-buffer — lands
// at the same demand BW). 16 lanes/edge, 16-edge chunks double-buffered.
__global__ __launch_bounds__(256) void edge_kernel(
    const unsigned short* __restrict__ Y,      // [N,256] bf16 (rows 512B)
    const int* __restrict__ eidx,              // [2,E] int32
    const float* __restrict__ w2,              // [128,2]
    const float* __restrict__ b2,              // [2]
    float* __restrict__ out,                   // [E,2]
    int E, int n_nodes)
{
    const int tid = threadIdx.x;
    const int lane = tid & 63, wave = tid >> 6;
    const int r = lane >> 4, cl = lane & 15;

    float w20[8], w21[8];                      // W2 slice for ch c = cl*8 + j
#pragma unroll
    for (int q = 0; q < 4; q++) {
        const float4 f = *(const float4*)&w2[cl * 16 + q * 4];
        w20[q * 2]     = f.x; w21[q * 2]     = f.y;
        w20[q * 2 + 1] = f.z; w21[q * 2 + 1] = f.w;
    }
    const float bb0 = b2[0], bb1 = b2[1];

    const long eb = (long)blockIdx.x * 256 + wave * 64;
    const char* Yb = (const char*)Y;

    int sg[4], dg[4];
    short8 buf[2][2][4];                       // [phase][src/dst][group]

#define LOAD_IDX(CH)                                                        \
    _Pragma("unroll")                                                       \
    for (int g = 0; g < 4; g++) {                                           \
        long e = eb + (CH) * 16 + g * 4 + r; if (e >= E) e = E - 1;         \
        int s = __builtin_nontemporal_load(&eidx[e]);                       \
        int d = __builtin_nontemporal_load(&eidx[(long)E + e]);             \
        sg[g] = (s < 0) ? 0 : (s >= n_nodes ? n_nodes - 1 : s);             \
        dg[g] = (d < 0) ? 0 : (d >= n_nodes ? n_nodes - 1 : d);             \
    }
#define LOAD_Y(P)                                                           \
    _Pragma("unroll")                                                       \
    for (int g = 0; g < 4; g++) {                                           \
        buf[P][0][g] = *(const short8*)(Yb + (size_t)sg[g] * 512 + cl * 16);\
        buf[P][1][g] = *(const short8*)(Yb + (size_t)dg[g] * 512 + 256      \
                                        + cl * 16);                         \
    }

    LOAD_IDX(0); LOAD_Y(0);
    LOAD_IDX(1); LOAD_Y(1);

    for (int ch = 0; ch < 4; ch++) {
        const int p = ch & 1;
        if (ch < 2) { LOAD_IDX(ch + 2); }      // idx for the refill below
#pragma unroll
        for (int g = 0; g < 4; g++) {
            float p0 = 0.f, p1 = 0.f;
#pragma unroll
            for (int j = 0; j < 8; j++) {
                float f = bf2f(buf[p][0][g][j]) + bf2f(buf[p][1][g][j]);
                f = fmaxf(f, 0.f);             // b1 folded into Y1
                p0 = fmaf(f, w20[j], p0);
                p1 = fmaf(f, w21[j], p1);
            }
#pragma unroll
            for (int m = 1; m < 16; m <<= 1) { // reduce over 16 cl-lanes
                p0 += __shfl_xor(p0, m, 64);
                p1 += __shfl_xor(p1, m, 64);
            }
            if (cl == 0) {
                const long e = eb + ch * 16 + g * 4 + r;
                if (e < E) {
                    floatx2 o;
                    o.x = p0 + bb0; o.y = p1 + bb1;
                    __builtin_nontemporal_store(o, (floatx2*)&out[e * 2]);
                }
            }
        }
        if (ch < 2) { LOAD_Y(p); }             // refill freed buffer (chunk ch+2)
    }
#undef LOAD_IDX
#undef LOAD_Y
}

extern "C" void kernel_launch(void* const* d_in, const int* in_sizes, int n_in,
                              void* d_out, int out_size, void* d_ws, size_t ws_size,
                              hipStream_t stream) {
    float*       xy   = (float*)d_in[0];       // X fp32 in, Y bf16 out (in-place)
    const int*   eidx = (const int*)d_in[1];
    const float* W1   = (const float*)d_in[2];
    const float* b1   = (const float*)d_in[3];
    const float* W2   = (const float*)d_in[4];
    const float* b2   = (const float*)d_in[5];
    float* out = (float*)d_out;

    const int n_node_elems = in_sizes[0];      // N*128
    const int N = n_node_elems / 128;
    const int E = in_sizes[1] / 2;

    unsigned short* wt = (unsigned short*)d_ws;  // 64KB

    cvt_wt_kernel<<<8, 256, 0, stream>>>(W1, wt);

    const int nblk1 = (N + 127) / 128;
    node_gemm_kernel<<<nblk1, 512, 0, stream>>>(xy, wt, b1, N);

    const int nblk2 = (E + 255) / 256;
    edge_kernel<<<nblk2, 256, 0, stream>>>((const unsigned short*)xy, eidx,
                                           W2, b2, out, E, N);
}

// Round 9
// 163.031 us; speedup vs baseline: 1.0516x; 1.0516x over previous
//
#include <hip/hip_runtime.h>

typedef __attribute__((ext_vector_type(8))) short short8;
typedef __attribute__((ext_vector_type(4))) short short4v;
typedef __attribute__((ext_vector_type(4))) float floatx4;
typedef __attribute__((ext_vector_type(2))) float floatx2;  // native vec: ok for NT builtins

// fp32 -> bf16 round-to-nearest-even (inputs finite)
static __device__ __forceinline__ unsigned short f2bf(float f) {
    union { float f; unsigned int u; } v; v.f = f;
    unsigned int u = v.u;
    return (unsigned short)((u + 0x7FFFu + ((u >> 16) & 1u)) >> 16);
}
static __device__ __forceinline__ float bf2f(short x) {
    return __uint_as_float(((unsigned int)(unsigned short)x) << 16);
}

// W1 [256,128] fp32 -> WT [256,128] bf16:
//   n' <  128: WT[n'][k] = W1[k][n']        (Y1 cols, k = top half)
//   n' >= 128: WT[n'][k] = W1[128+k][n'-128] (Y2 cols, k = bottom half)
__global__ void cvt_wt_kernel(const float* __restrict__ w1,
                              unsigned short* __restrict__ wt) {
    __shared__ unsigned short sT[32 * 130];
    const int b = blockIdx.x;            // 0..7 -> W1 k-rows [b*32, b*32+32)
    const int kg0 = b * 32;
    const int h = (kg0 >= 128) ? 1 : 0;
    const int kk0 = kg0 & 127;
    const int tid = threadIdx.x;
#pragma unroll
    for (int i = 0; i < 16; i++) {       // load 32x128, coalesced in n
        int idx = tid + i * 256;
        int k = idx >> 7, n = idx & 127;
        sT[k * 130 + n] = f2bf(w1[(kg0 + k) * 128 + n]);
    }
    __syncthreads();
#pragma unroll
    for (int i = 0; i < 16; i++) {       // store, coalesced in k
        int idx = tid + i * 256;
        int n = idx >> 5, k = idx & 31;
        wt[(h * 128 + n) * 128 + kk0 + k] = sT[k * 130 + n];
    }
}

// Phase 1 (r6-proven variant, exact revert): Y[n] = [x_n@W1_top + b1 | x_n@W1_bot],
// bf16, IN-PLACE over X. W in LDS (64KB), per-lane row loads, 512 thr.
// r7/r8 "X-in-LDS" alternatives regressed the TOTAL by ~7 µs across two
// sessions (164.0 -> 170.6/171.4) despite plausible per-kernel gains — the
// system (edge handover / DVFS) prefers this form. Keep it.
// In-place safety: each lane reads only its own row; all loads precede all
// stores in program order; blocks own disjoint rows. xy NOT __restrict__.
__global__ __launch_bounds__(512, 4) void node_gemm_kernel(
    float* xy,                                 // in: X fp32 [N,128]; out: Y bf16 [N,256]
    const unsigned short* __restrict__ wt,     // [256,128] bf16 (pre-transposed)
    const float* __restrict__ b1, int N)
{
    __shared__ unsigned short sW[256 * 128];   // 64KB, slot-swizzled

    const int tid = threadIdx.x;
    const int lane = tid & 63, wave = tid >> 6;
    const int l15 = lane & 15, lq = lane >> 4;

    // Stage WT: 16B slot s of row r stored at slot s^(r&15).
#pragma unroll
    for (int i = 0; i < 8; i++) {
        int u = tid + i * 512;                 // 0..4095 16B-units
        int r = u >> 4, s = u & 15;
        *(short8*)&sW[r * 128 + ((s ^ r) & 15) * 8] =
            *(const short8*)&wt[r * 128 + s * 8];
    }
    __syncthreads();

    const int nr = blockIdx.x * 128 + wave * 16 + l15;
    const int nc = (nr < N) ? nr : (N - 1);
    const float* xrow = xy + (size_t)nc * 128;

    floatx4 acc[16];
#pragma unroll
    for (int mt = 0; mt < 16; mt++) acc[mt] = (floatx4){0.f, 0.f, 0.f, 0.f};

#pragma unroll
    for (int kh = 0; kh < 2; kh++) {           // two k-halves of 64
        float4 xf[4];
#pragma unroll
        for (int q = 0; q < 4; q++)            // 4 loads in flight
            xf[q] = *(const float4*)(xrow + kh * 64 + (q >> 1) * 32 + lq * 8
                                     + (q & 1) * 4);
        short8 bf[2];
#pragma unroll
        for (int t = 0; t < 2; t++) {
            bf[t][0] = (short)f2bf(xf[2 * t].x);
            bf[t][1] = (short)f2bf(xf[2 * t].y);
            bf[t][2] = (short)f2bf(xf[2 * t].z);
            bf[t][3] = (short)f2bf(xf[2 * t].w);
            bf[t][4] = (short)f2bf(xf[2 * t + 1].x);
            bf[t][5] = (short)f2bf(xf[2 * t + 1].y);
            bf[t][6] = (short)f2bf(xf[2 * t + 1].z);
            bf[t][7] = (short)f2bf(xf[2 * t + 1].w);
        }
#pragma unroll
        for (int t = 0; t < 2; t++) {
            const int ks = kh * 2 + t;
#pragma unroll
            for (int mt = 0; mt < 16; mt++) {
                const short8 af = *(const short8*)
                    &sW[(mt * 16 + l15) * 128 + (((ks * 4 + lq) ^ l15) & 15) * 8];
                acc[mt] = __builtin_amdgcn_mfma_f32_16x16x32_bf16(af, bf[t],
                                                                  acc[mt], 0, 0, 0);
            }
        }
    }

    if (nr < N) {
        unsigned short* yrow = (unsigned short*)xy + (size_t)nr * 256;
#pragma unroll
        for (int mt = 0; mt < 16; mt++) {
            const int oc = mt * 16 + lq * 4;   // out-col base (C row = lq*4+i)
            float4 bb = (mt < 8) ? *(const float4*)&b1[oc]
                                 : (float4){0.f, 0.f, 0.f, 0.f};
            short4v pk;
            pk[0] = (short)f2bf(acc[mt][0] + bb.x);
            pk[1] = (short)f2bf(acc[mt][1] + bb.y);
            pk[2] = (short)f2bf(acc[mt][2] + bb.z);
            pk[3] = (short)f2bf(acc[mt][3] + bb.w);
            *(short4v*)(yrow + oc) = pk;       // 8B store
        }
    }
}

// Phase 2: pure gather + reduce. out[e] = relu(Y1[s]+Y2[d]) @ W2 + b2.
// FROZEN at the measured per-CU demand ceiling (~6.7 TB/s at L1-miss level;
// r1-r6: every structure — occupancy 2x, barrier-free, double-buffer — lands
// at the same demand BW). 16 lanes/edge, 16-edge chunks double-buffered.
__global__ __launch_bounds__(256) void edge_kernel(
    const unsigned short* __restrict__ Y,      // [N,256] bf16 (rows 512B)
    const int* __restrict__ eidx,              // [2,E] int32
    const float* __restrict__ w2,              // [128,2]
    const float* __restrict__ b2,              // [2]
    float* __restrict__ out,                   // [E,2]
    int E, int n_nodes)
{
    const int tid = threadIdx.x;
    const int lane = tid & 63, wave = tid >> 6;
    const int r = lane >> 4, cl = lane & 15;

    float w20[8], w21[8];                      // W2 slice for ch c = cl*8 + j
#pragma unroll
    for (int q = 0; q < 4; q++) {
        const float4 f = *(const float4*)&w2[cl * 16 + q * 4];
        w20[q * 2]     = f.x; w21[q * 2]     = f.y;
        w20[q * 2 + 1] = f.z; w21[q * 2 + 1] = f.w;
    }
    const float bb0 = b2[0], bb1 = b2[1];

    const long eb = (long)blockIdx.x * 256 + wave * 64;
    const char* Yb = (const char*)Y;

    int sg[4], dg[4];
    short8 buf[2][2][4];                       // [phase][src/dst][group]

#define LOAD_IDX(CH)                                                        \
    _Pragma("unroll")                                                       \
    for (int g = 0; g < 4; g++) {                                           \
        long e = eb + (CH) * 16 + g * 4 + r; if (e >= E) e = E - 1;         \
        int s = __builtin_nontemporal_load(&eidx[e]);                       \
        int d = __builtin_nontemporal_load(&eidx[(long)E + e]);             \
        sg[g] = (s < 0) ? 0 : (s >= n_nodes ? n_nodes - 1 : s);             \
        dg[g] = (d < 0) ? 0 : (d >= n_nodes ? n_nodes - 1 : d);             \
    }
#define LOAD_Y(P)                                                           \
    _Pragma("unroll")                                                       \
    for (int g = 0; g < 4; g++) {                                           \
        buf[P][0][g] = *(const short8*)(Yb + (size_t)sg[g] * 512 + cl * 16);\
        buf[P][1][g] = *(const short8*)(Yb + (size_t)dg[g] * 512 + 256      \
                                        + cl * 16);                         \
    }

    LOAD_IDX(0); LOAD_Y(0);
    LOAD_IDX(1); LOAD_Y(1);

    for (int ch = 0; ch < 4; ch++) {
        const int p = ch & 1;
        if (ch < 2) { LOAD_IDX(ch + 2); }      // idx for the refill below
#pragma unroll
        for (int g = 0; g < 4; g++) {
            float p0 = 0.f, p1 = 0.f;
#pragma unroll
            for (int j = 0; j < 8; j++) {
                float f = bf2f(buf[p][0][g][j]) + bf2f(buf[p][1][g][j]);
                f = fmaxf(f, 0.f);             // b1 folded into Y1
                p0 = fmaf(f, w20[j], p0);
                p1 = fmaf(f, w21[j], p1);
            }
#pragma unroll
            for (int m = 1; m < 16; m <<= 1) { // reduce over 16 cl-lanes
                p0 += __shfl_xor(p0, m, 64);
                p1 += __shfl_xor(p1, m, 64);
            }
            if (cl == 0) {
                const long e = eb + ch * 16 + g * 4 + r;
                if (e < E) {
                    floatx2 o;
                    o.x = p0 + bb0; o.y = p1 + bb1;
                    __builtin_nontemporal_store(o, (floatx2*)&out[e * 2]);
                }
            }
        }
        if (ch < 2) { LOAD_Y(p); }             // refill freed buffer (chunk ch+2)
    }
#undef LOAD_IDX
#undef LOAD_Y
}

extern "C" void kernel_launch(void* const* d_in, const int* in_sizes, int n_in,
                              void* d_out, int out_size, void* d_ws, size_t ws_size,
                              hipStream_t stream) {
    float*       xy   = (float*)d_in[0];       // X fp32 in, Y bf16 out (in-place)
    const int*   eidx = (const int*)d_in[1];
    const float* W1   = (const float*)d_in[2];
    const float* b1   = (const float*)d_in[3];
    const float* W2   = (const float*)d_in[4];
    const float* b2   = (const float*)d_in[5];
    float* out = (float*)d_out;

    const int n_node_elems = in_sizes[0];      // N*128
    const int N = n_node_elems / 128;
    const int E = in_sizes[1] / 2;

    unsigned short* wt = (unsigned short*)d_ws;  // 64KB

    cvt_wt_kernel<<<8, 256, 0, stream>>>(W1, wt);

    const int nblk1 = (N + 127) / 128;
    node_gemm_kernel<<<nblk1, 512, 0, stream>>>(xy, wt, b1, N);

    const int nblk2 = (E + 255) / 256;
    edge_kernel<<<nblk2, 256, 0, stream>>>((const unsigned short*)xy, eidx,
                                           W2, b2, out, E, N);
}